// Round 5
// baseline (575.381 us; speedup 1.0000x reference)
//
#include <hip/hip_runtime.h>
#include <hip/hip_bf16.h>

// WindowAttention — fused kernel, wave-owns-head design.
// Inputs fp32, compute bf16 MFMA, output fp32.
// B=1024 windows, N=64 tokens, H=8 heads, hd=32, DIM=256, P=4.
// Block = 256 threads (4 waves); wave w owns heads {2w, 2w+1} end-to-end.
// Per-wave private LDS scratch (Q/K/Vt, P overlays Q||K) -> no barriers until proj.
// LDS total 59392 B -> 2 blocks/CU. Fourier biases folded into QK^T as 16 extra
// K-dims (numerics identical to round-3-verified mapping).

using short8  = __attribute__((ext_vector_type(8))) short;
using floatx4 = __attribute__((ext_vector_type(4))) float;

#define PI_F    3.14159265358979323846f
#define SCALE_F 0.17677669529663687f   // 32^-0.5

__device__ __forceinline__ short bsh(float x) {
  __hip_bfloat16 h = __float2bfloat16(x);
  return *reinterpret_cast<short*>(&h);
}
__device__ __forceinline__ short8 pack8(float4 a, float4 b) {
  short8 r;
  r[0] = bsh(a.x); r[1] = bsh(a.y); r[2] = bsh(a.z); r[3] = bsh(a.w);
  r[4] = bsh(b.x); r[5] = bsh(b.y); r[6] = bsh(b.z); r[7] = bsh(b.w);
  return r;
}

// ---------------- kernel 1: weights fp32 -> bf16 into ws ----------------
__global__ void prep_kernel(const float* __restrict__ qw,
                            const float* __restrict__ pw,
                            __hip_bfloat16* __restrict__ dst) {
  int g = blockIdx.x * 256 + threadIdx.x;   // 32768 threads, 8 floats each
  const float4* src;
  short8* d;
  if (g < 24576) { src = (const float4*)qw + 2 * g; d = (short8*)dst + g; }
  else { int g2 = g - 24576; src = (const float4*)pw + 2 * g2; d = (short8*)(dst + 196608) + g2; }
  *d = pack8(src[0], src[1]);
}

// ---------------- kernel 2: fully fused per-window ----------------
__global__ __launch_bounds__(256, 2) void fused_kernel(
    const float* __restrict__ x, const float* __restrict__ D,
    const float* __restrict__ a_p, const float* __restrict__ b_p,
    const float* __restrict__ a_r, const float* __restrict__ b_r,
    const __hip_bfloat16* __restrict__ wq, const float* __restrict__ qkv_b,
    const __hip_bfloat16* __restrict__ pwb, const float* __restrict__ pb,
    float* __restrict__ out)
{
  // per-wave scratch: Q[64][40] @0, K[64][40] @2560, Vt[32][72] @5120 (elems)
  // P[64][72] overlays Q||K; O[64][264] overlays everything (after barrier).
  __shared__ __align__(16) __hip_bfloat16 sLds[4 * 7424];   // 59392 B

  const int tid = threadIdx.x;
  const int lane = tid & 63, w = tid >> 6;      // 4 waves
  const int laneN = lane & 15, laneQ = lane >> 4;
  const int b = blockIdx.x;
  const floatx4 fzero = {0.f, 0.f, 0.f, 0.f};
  const short8 zero8 = {0, 0, 0, 0, 0, 0, 0, 0};

  __hip_bfloat16* Q  = &sLds[w * 7424];
  __hip_bfloat16* K  = Q + 2560;
  __hip_bfloat16* Vt = Q + 5120;
  __hip_bfloat16* Pp = Q;          // overlay
  __hip_bfloat16* sO = &sLds[0];   // overlay [64][264] after barrier

  const float* xb = x + (size_t)b * 16384;

  // ---- per-lane Fourier features (head-independent), tokens t = tt*16+laneN ----
  // f8[tt][0..7] = laneQ==0 ? {c1..c4,s1..s4}(radius) : {ca1..ca4,sa1..sa4}(azimuth)
  float f8[4][8];
  short8 qf1[4];
  {
    // azimuth depends only on laneN&7 (token col), same for all tt
    float sa1, ca1; __sincosf((2.f * PI_F / 64.f) * (float)(laneN & 7), &sa1, &ca1);
    float ca2 = ca1*ca1 - sa1*sa1, sa2 = 2.f*sa1*ca1;
    float ca3 = ca2*ca1 - sa2*sa1, sa3 = sa2*ca1 + ca2*sa1;
    float ca4 = ca2*ca2 - sa2*sa2, sa4 = 2.f*sa2*ca2;
    short8 qaz;
    qaz[0]=bsh(ca1); qaz[1]=bsh(ca2); qaz[2]=bsh(ca3); qaz[3]=bsh(ca4);
    qaz[4]=bsh(sa1); qaz[5]=bsh(sa2); qaz[6]=bsh(sa3); qaz[7]=bsh(sa4);
    #pragma unroll
    for (int tt = 0; tt < 4; ++tt) {
      float dv = D[b * 64 + tt * 16 + laneN];
      float s1, c1; __sincosf(PI_F * dv, &s1, &c1);
      float c2 = c1*c1 - s1*s1, s2 = 2.f*s1*c1;
      float c3 = c2*c1 - s2*s1, s3 = s2*c1 + c2*s1;
      float c4 = c2*c2 - s2*s2, s4 = 2.f*s2*c2;
      if (laneQ == 0) {
        f8[tt][0]=c1; f8[tt][1]=c2; f8[tt][2]=c3; f8[tt][3]=c4;
        f8[tt][4]=s1; f8[tt][5]=s2; f8[tt][6]=s3; f8[tt][7]=s4;
      } else {
        f8[tt][0]=ca1; f8[tt][1]=ca2; f8[tt][2]=ca3; f8[tt][3]=ca4;
        f8[tt][4]=sa1; f8[tt][5]=sa2; f8[tt][6]=sa3; f8[tt][7]=sa4;
      }
      short8 qrad;
      qrad[0]=bsh(c1); qrad[1]=bsh(c2); qrad[2]=bsh(c3); qrad[3]=bsh(c4);
      qrad[4]=bsh(s1); qrad[5]=bsh(s2); qrad[6]=bsh(s3); qrad[7]=bsh(s4);
      qf1[tt] = (laneQ == 0) ? qrad : ((laneQ == 1) ? qaz : zero8);
    }
  }

  floatx4 oacc[2][4][2];

  #pragma unroll
  for (int hi = 0; hi < 2; ++hi) {
    const int h = w * 2 + hi;

    // ---- qkv GEMM for head h: (64x256) @ (256x96), kk-outer, 24 indep chains ----
    int col0s[6];
    #pragma unroll
    for (int ni = 0; ni < 6; ++ni)
      col0s[ni] = (ni < 2) ? h * 32 + ni * 16
                : (ni < 4) ? 256 + h * 32 + (ni - 2) * 16
                           : 512 + h * 32 + (ni - 4) * 16;
    floatx4 acc[6][4];
    #pragma unroll
    for (int ni = 0; ni < 6; ++ni)
      #pragma unroll
      for (int mt = 0; mt < 4; ++mt) acc[ni][mt] = fzero;

    #pragma unroll
    for (int kk = 0; kk < 8; ++kk) {
      short8 a4[4];
      #pragma unroll
      for (int mt = 0; mt < 4; ++mt) {
        const float4* p = (const float4*)(xb + (mt * 16 + laneN) * 256 + kk * 32 + laneQ * 8);
        a4[mt] = pack8(p[0], p[1]);
      }
      #pragma unroll
      for (int ni = 0; ni < 6; ++ni) {
        short8 bq = *(const short8*)&wq[(size_t)(col0s[ni] + laneN) * 256 + kk * 32 + laneQ * 8];
        #pragma unroll
        for (int mt = 0; mt < 4; ++mt)
          acc[ni][mt] = __builtin_amdgcn_mfma_f32_16x16x32_bf16(a4[mt], bq, acc[ni][mt], 0, 0, 0);
      }
    }
    // writeback: Q (scaled), K, Vt (transposed) — wave-private scratch
    #pragma unroll
    for (int ni = 0; ni < 6; ++ni) {
      float bias = qkv_b[col0s[ni] + laneN];
      #pragma unroll
      for (int mt = 0; mt < 4; ++mt)
        #pragma unroll
        for (int r = 0; r < 4; ++r) {
          int row = mt * 16 + laneQ * 4 + r;     // C-layout: col=laneN, row=laneQ*4+r
          float v = acc[ni][mt][r] + bias;
          if (ni < 2)
            Q[row * 40 + ni * 16 + laneN] = __float2bfloat16(v * SCALE_F);
          else if (ni < 4)
            K[row * 40 + (ni - 2) * 16 + laneN] = __float2bfloat16(v);
          else
            Vt[((ni - 4) * 16 + laneN) * 72 + row] = __float2bfloat16(v);
        }
    }

    // ---- K-side mixed-feature fragments (registers only) ----
    short8 kf1[4];
    {
      float A[4], Bp[4];
      #pragma unroll
      for (int j = 0; j < 4; ++j) {
        float arj = a_r[(j + 1) * 8 + h], apj = a_p[(j + 1) * 8 + h];
        float brj = b_r[j * 8 + h],       bpj = b_p[j * 8 + h];
        A[j]  = 0.25f * ((laneQ == 0) ? arj : apj);
        Bp[j] = 0.25f * ((laneQ == 0) ? brj : -bpj);
      }
      #pragma unroll
      for (int tt = 0; tt < 4; ++tt) {
        short8 m;
        #pragma unroll
        for (int j = 0; j < 4; ++j) {
          m[j]     = bsh(A[j] * f8[tt][j]     + Bp[j] * f8[tt][4 + j]);
          m[4 + j] = bsh(A[j] * f8[tt][4 + j] - Bp[j] * f8[tt][j]);
        }
        kf1[tt] = (laneQ < 2) ? m : zero8;
      }
    }

    // ---- S = Q~ K~^T (wave-internal LDS read-back; lgkmcnt only) ----
    short8 qf0[4], kf0[4], vb[2][2];
    #pragma unroll
    for (int mt = 0; mt < 4; ++mt)
      qf0[mt] = *(const short8*)&Q[(mt * 16 + laneN) * 40 + laneQ * 8];
    #pragma unroll
    for (int nt = 0; nt < 4; ++nt)
      kf0[nt] = *(const short8*)&K[(nt * 16 + laneN) * 40 + laneQ * 8];
    #pragma unroll
    for (int ont = 0; ont < 2; ++ont)
      #pragma unroll
      for (int kk = 0; kk < 2; ++kk)
        vb[ont][kk] = *(const short8*)&Vt[(ont * 16 + laneN) * 72 + kk * 32 + laneQ * 8];

    floatx4 s[4][4];
    #pragma unroll
    for (int mt = 0; mt < 4; ++mt)
      #pragma unroll
      for (int nt = 0; nt < 4; ++nt) {
        s[mt][nt] = __builtin_amdgcn_mfma_f32_16x16x32_bf16(qf0[mt], kf0[nt], fzero, 0, 0, 0);
        s[mt][nt] = __builtin_amdgcn_mfma_f32_16x16x32_bf16(qf1[mt], kf1[nt], s[mt][nt], 0, 0, 0);
      }

    // ---- softmax (per 16-row stripe; reduce over laneN via xor-shuffles) -> P ----
    #pragma unroll
    for (int mt = 0; mt < 4; ++mt) {
      #pragma unroll
      for (int r = 0; r < 4; ++r) {
        float mx = fmaxf(fmaxf(s[mt][0][r], s[mt][1][r]), fmaxf(s[mt][2][r], s[mt][3][r]));
        mx = fmaxf(mx, __shfl_xor(mx, 1));
        mx = fmaxf(mx, __shfl_xor(mx, 2));
        mx = fmaxf(mx, __shfl_xor(mx, 4));
        mx = fmaxf(mx, __shfl_xor(mx, 8));
        float e0 = __expf(s[mt][0][r] - mx), e1 = __expf(s[mt][1][r] - mx);
        float e2 = __expf(s[mt][2][r] - mx), e3 = __expf(s[mt][3][r] - mx);
        float sum = e0 + e1 + e2 + e3;
        sum += __shfl_xor(sum, 1);
        sum += __shfl_xor(sum, 2);
        sum += __shfl_xor(sum, 4);
        sum += __shfl_xor(sum, 8);
        float inv = __builtin_amdgcn_rcpf(sum);
        int row = mt * 16 + laneQ * 4 + r;      // P overlays Q||K (both consumed)
        Pp[row * 72 +  0 + laneN] = __float2bfloat16(e0 * inv);
        Pp[row * 72 + 16 + laneN] = __float2bfloat16(e1 * inv);
        Pp[row * 72 + 32 + laneN] = __float2bfloat16(e2 * inv);
        Pp[row * 72 + 48 + laneN] = __float2bfloat16(e3 * inv);
      }
    }

    // ---- O = P @ V ----
    #pragma unroll
    for (int mt = 0; mt < 4; ++mt) {
      short8 pf0 = *(const short8*)&Pp[(mt * 16 + laneN) * 72 + laneQ * 8];
      short8 pf1 = *(const short8*)&Pp[(mt * 16 + laneN) * 72 + 32 + laneQ * 8];
      #pragma unroll
      for (int ont = 0; ont < 2; ++ont) {
        oacc[hi][mt][ont] = __builtin_amdgcn_mfma_f32_16x16x32_bf16(pf0, vb[ont][0], fzero, 0, 0, 0);
        oacc[hi][mt][ont] = __builtin_amdgcn_mfma_f32_16x16x32_bf16(pf1, vb[ont][1], oacc[hi][mt][ont], 0, 0, 0);
      }
    }
  }

  // ---- stage O into shared LDS (overlays all scratch), then proj ----
  __syncthreads();   // all waves done with private scratch
  #pragma unroll
  for (int hi = 0; hi < 2; ++hi)
    #pragma unroll
    for (int mt = 0; mt < 4; ++mt)
      #pragma unroll
      for (int ont = 0; ont < 2; ++ont)
        #pragma unroll
        for (int r = 0; r < 4; ++r)
          sO[(mt * 16 + laneQ * 4 + r) * 264 + (w * 2 + hi) * 32 + ont * 16 + laneN] =
              __float2bfloat16(oacc[hi][mt][ont][r]);
  __syncthreads();

  // proj: wave w -> out cols [w*64, w*64+64)
  floatx4 pacc[4][4];
  #pragma unroll
  for (int mt = 0; mt < 4; ++mt)
    #pragma unroll
    for (int nt = 0; nt < 4; ++nt) pacc[mt][nt] = fzero;
  #pragma unroll
  for (int kk = 0; kk < 8; ++kk) {
    short8 pa[4], pbf[4];
    #pragma unroll
    for (int mt = 0; mt < 4; ++mt)
      pa[mt] = *(const short8*)&sO[(mt * 16 + laneN) * 264 + kk * 32 + laneQ * 8];
    #pragma unroll
    for (int nt = 0; nt < 4; ++nt)
      pbf[nt] = *(const short8*)&pwb[(size_t)(w * 64 + nt * 16 + laneN) * 256 + kk * 32 + laneQ * 8];
    #pragma unroll
    for (int mt = 0; mt < 4; ++mt)
      #pragma unroll
      for (int nt = 0; nt < 4; ++nt)
        pacc[mt][nt] = __builtin_amdgcn_mfma_f32_16x16x32_bf16(pa[mt], pbf[nt], pacc[mt][nt], 0, 0, 0);
  }
  float* og = out + (size_t)b * 16384;
  #pragma unroll
  for (int nt = 0; nt < 4; ++nt) {
    float bias = pb[w * 64 + nt * 16 + laneN];
    #pragma unroll
    for (int mt = 0; mt < 4; ++mt)
      #pragma unroll
      for (int r = 0; r < 4; ++r)
        og[(mt * 16 + laneQ * 4 + r) * 256 + w * 64 + nt * 16 + laneN] =
            pacc[mt][nt][r] + bias;
  }
}

extern "C" void kernel_launch(void* const* d_in, const int* in_sizes, int n_in,
                              void* d_out, int out_size, void* d_ws, size_t ws_size,
                              hipStream_t stream) {
  const float* x      = (const float*)d_in[0];
  const float* D      = (const float*)d_in[1];
  const float* a_p    = (const float*)d_in[2];
  const float* b_p    = (const float*)d_in[3];
  const float* a_r    = (const float*)d_in[4];
  const float* b_r    = (const float*)d_in[5];
  const float* qkv_w  = (const float*)d_in[6];
  const float* qkv_b  = (const float*)d_in[7];
  const float* proj_w = (const float*)d_in[8];
  const float* proj_b = (const float*)d_in[9];

  __hip_bfloat16* wq  = (__hip_bfloat16*)d_ws;   // 196608 bf16 (qkv_w)
  __hip_bfloat16* pwb = wq + 196608;             // 65536 bf16 (proj_w)
  float* out = (float*)d_out;

  prep_kernel<<<128, 256, 0, stream>>>(qkv_w, proj_w, wq);
  fused_kernel<<<1024, 256, 0, stream>>>(x, D, a_p, b_p, a_r, b_r, wq, qkv_b,
                                         pwb, proj_b, out);
}

// Round 6
// 213.980 us; speedup vs baseline: 2.6890x; 2.6890x over previous
//
#include <hip/hip_runtime.h>
#include <hip/hip_bf16.h>

// WindowAttention — fused per-window kernel, wave-owns-2-heads, swizzled LDS.
// Inputs fp32, compute bf16 MFMA, output fp32.
// B=1024 windows, N=64 tokens, H=8 heads, hd=32, DIM=256, P=4.
// Block = 256 threads (4 waves); wave w owns heads {2w, 2w+1} end-to-end.
// LDS = 81920 B exactly -> 2 blocks/CU (8 waves/CU, two independent barrier
// domains). 3 barriers total; qkv->attn->softmax->PV runs barrier-free per wave.
// All LDS arrays flat with 16B-chunk XOR swizzle (2-way conflicts = free).
// Weights pre-packed (prep_kernel) into MFMA-fragment-linear order so every
// B-load is a fully coalesced 1KB/wave dwordx4.
// Fourier biases folded into QK^T as 16 extra K-dims (r3/r4/r5-verified math).

using short8  = __attribute__((ext_vector_type(8))) short;
using floatx4 = __attribute__((ext_vector_type(4))) float;

#define PI_F    3.14159265358979323846f
#define SCALE_F 0.17677669529663687f   // 32^-0.5

__device__ __forceinline__ short bsh(float x) {
  __hip_bfloat16 h = __float2bfloat16(x);
  return *reinterpret_cast<short*>(&h);
}
__device__ __forceinline__ short8 pack8(float4 a, float4 b) {
  short8 r;
  r[0] = bsh(a.x); r[1] = bsh(a.y); r[2] = bsh(a.z); r[3] = bsh(a.w);
  r[4] = bsh(b.x); r[5] = bsh(b.y); r[6] = bsh(b.z); r[7] = bsh(b.w);
  return r;
}

// ---------------- kernel 1: pack weights bf16, MFMA-fragment-linear ----------------
// chunk g < 24576: qkv tile t=g>>9 (48 tiles of 16 cols), kk=(g>>6)&7, lane=g&63
// chunk g >= 24576: proj tile (g-24576)>>9 (16 tiles)
// chunk value[j] = W[(t*16+laneN)*256 + kk*32 + laneQ*8 + j]
__global__ void prep_kernel(const float* __restrict__ qw,
                            const float* __restrict__ pw,
                            __hip_bfloat16* __restrict__ dst) {
  int g = blockIdx.x * 256 + threadIdx.x;   // 32768 chunks
  int kk = (g >> 6) & 7, lane = g & 63;
  int laneN = lane & 15, laneQ = lane >> 4;
  const float* src;
  if (g < 24576) {
    int t = g >> 9;
    src = qw + (size_t)(t * 16 + laneN) * 256 + kk * 32 + laneQ * 8;
  } else {
    int t = (g - 24576) >> 9;
    src = pw + (size_t)(t * 16 + laneN) * 256 + kk * 32 + laneQ * 8;
  }
  const float4* s4 = (const float4*)src;
  *((short8*)dst + g) = pack8(s4[0], s4[1]);
}

// ---------------- kernel 2: fully fused per-window ----------------
__global__ __launch_bounds__(256, 2) void fused_kernel(
    const float* __restrict__ x, const float* __restrict__ D,
    const float* __restrict__ a_p, const float* __restrict__ b_p,
    const float* __restrict__ a_r, const float* __restrict__ b_r,
    const __hip_bfloat16* __restrict__ wqP, const float* __restrict__ qkv_b,
    const __hip_bfloat16* __restrict__ pwP, const float* __restrict__ pb,
    float* __restrict__ out)
{
  __shared__ __align__(16) __hip_bfloat16 sM[40960];   // 81920 B exactly

  const int tid = threadIdx.x;
  const int lane = tid & 63, w = tid >> 6;      // 4 waves
  const int laneN = lane & 15, laneQ = lane >> 4;
  const int b = blockIdx.x;
  const floatx4 fzero = {0.f, 0.f, 0.f, 0.f};
  const short8 zero8 = {0, 0, 0, 0, 0, 0, 0, 0};

  __hip_bfloat16* sX = sM;                      // [64][256] swizzled; sO overlay later
  __hip_bfloat16* Qs = sM + 16384 + w * 6144;   // [64][32] swizzled (wave-private)
  __hip_bfloat16* Ks = Qs + 2048;               // [64][32] swizzled
  __hip_bfloat16* Vs = Qs + 4096;               // Vt [32][64] swizzled
  __hip_bfloat16* Ps = Qs;                      // P [64][64] swizzled, overlays Q||K

  // ---- stage x -> sX (fp32->bf16, swizzled chunks) ----
  const float* xb = x + (size_t)b * 16384;
  #pragma unroll
  for (int it = 0; it < 8; ++it) {
    int g = tid + it * 256;                     // chunk index in [0,2048)
    int t = g >> 5, c8 = g & 31;
    const float4* p = (const float4*)(xb + t * 256 + c8 * 8);
    *(short8*)&sX[t * 256 + ((c8 ^ (t & 7)) << 3)] = pack8(p[0], p[1]);
  }
  __syncthreads();   // barrier 1

  floatx4 oacc[2][4][2];

  #pragma unroll
  for (int hi = 0; hi < 2; ++hi) {
    const int h = w * 2 + hi;

    // ---- qkv for head h: 2 groups of 3 col-tiles (12 live accs) ----
    #pragma unroll
    for (int grp = 0; grp < 2; ++grp) {
      floatx4 acc[3][4];
      #pragma unroll
      for (int i = 0; i < 3; ++i)
        #pragma unroll
        for (int mt = 0; mt < 4; ++mt) acc[i][mt] = fzero;

      #pragma unroll
      for (int kk = 0; kk < 8; ++kk) {
        short8 a4[4];
        #pragma unroll
        for (int mt = 0; mt < 4; ++mt) {
          int t = mt * 16 + laneN;
          a4[mt] = *(const short8*)&sX[t * 256 + (((kk * 4 + laneQ) ^ (t & 7)) << 3)];
        }
        #pragma unroll
        for (int i = 0; i < 3; ++i) {
          int ni = grp * 3 + i;
          int tile = (ni < 2) ? h * 2 + ni
                   : (ni < 4) ? 16 + h * 2 + (ni - 2)
                              : 32 + h * 2 + (ni - 4);
          short8 bq = *(const short8*)&wqP[((size_t)(tile * 8 + kk) * 64 + lane) * 8];
          #pragma unroll
          for (int mt = 0; mt < 4; ++mt)
            acc[i][mt] = __builtin_amdgcn_mfma_f32_16x16x32_bf16(a4[mt], bq, acc[i][mt], 0, 0, 0);
        }
      }
      // writeback (C-layout: row=laneQ*4+r+16mt, col=laneN within 16-tile)
      #pragma unroll
      for (int i = 0; i < 3; ++i) {
        int ni = grp * 3 + i;
        int col0 = (ni < 2) ? h * 32 + ni * 16
                 : (ni < 4) ? 256 + h * 32 + (ni - 2) * 16
                            : 512 + h * 32 + (ni - 4) * 16;
        float bias = qkv_b[col0 + laneN];
        #pragma unroll
        for (int mt = 0; mt < 4; ++mt)
          #pragma unroll
          for (int r = 0; r < 4; ++r) {
            int row = mt * 16 + laneQ * 4 + r;
            float v = acc[i][mt][r] + bias;
            if (ni < 2) {
              int c4 = ni * 2 + (laneN >> 3);
              Qs[row * 32 + ((c4 ^ (row & 3)) << 3) + (laneN & 7)] =
                  __float2bfloat16(v * SCALE_F);
            } else if (ni < 4) {
              int c4 = (ni - 2) * 2 + (laneN >> 3);
              Ks[row * 32 + ((c4 ^ (row & 3)) << 3) + (laneN & 7)] =
                  __float2bfloat16(v);
            } else {
              int d = (ni - 4) * 16 + laneN;
              Vs[d * 64 + (((row >> 3) ^ (d & 7)) << 3) + (row & 7)] =
                  __float2bfloat16(v);
            }
          }
      }
    }

    // ---- Fourier features + bias fragments (registers; transient) ----
    short8 qf1[4], kf1[4];
    {
      float f8[4][8];
      float sa1, ca1; __sincosf((2.f * PI_F / 64.f) * (float)(laneN & 7), &sa1, &ca1);
      float ca2 = ca1*ca1 - sa1*sa1, sa2 = 2.f*sa1*ca1;
      float ca3 = ca2*ca1 - sa2*sa1, sa3 = sa2*ca1 + ca2*sa1;
      float ca4 = ca2*ca2 - sa2*sa2, sa4 = 2.f*sa2*ca2;
      short8 qaz;
      qaz[0]=bsh(ca1); qaz[1]=bsh(ca2); qaz[2]=bsh(ca3); qaz[3]=bsh(ca4);
      qaz[4]=bsh(sa1); qaz[5]=bsh(sa2); qaz[6]=bsh(sa3); qaz[7]=bsh(sa4);
      #pragma unroll
      for (int tt = 0; tt < 4; ++tt) {
        float dv = D[b * 64 + tt * 16 + laneN];
        float s1, c1; __sincosf(PI_F * dv, &s1, &c1);
        float c2 = c1*c1 - s1*s1, s2 = 2.f*s1*c1;
        float c3 = c2*c1 - s2*s1, s3 = s2*c1 + c2*s1;
        float c4 = c2*c2 - s2*s2, s4 = 2.f*s2*c2;
        if (laneQ == 0) {
          f8[tt][0]=c1; f8[tt][1]=c2; f8[tt][2]=c3; f8[tt][3]=c4;
          f8[tt][4]=s1; f8[tt][5]=s2; f8[tt][6]=s3; f8[tt][7]=s4;
        } else {
          f8[tt][0]=ca1; f8[tt][1]=ca2; f8[tt][2]=ca3; f8[tt][3]=ca4;
          f8[tt][4]=sa1; f8[tt][5]=sa2; f8[tt][6]=sa3; f8[tt][7]=sa4;
        }
        short8 qrad;
        qrad[0]=bsh(c1); qrad[1]=bsh(c2); qrad[2]=bsh(c3); qrad[3]=bsh(c4);
        qrad[4]=bsh(s1); qrad[5]=bsh(s2); qrad[6]=bsh(s3); qrad[7]=bsh(s4);
        qf1[tt] = (laneQ == 0) ? qrad : ((laneQ == 1) ? qaz : zero8);
      }
      float A[4], Bp[4];
      #pragma unroll
      for (int j = 0; j < 4; ++j) {
        float arj = a_r[(j + 1) * 8 + h], apj = a_p[(j + 1) * 8 + h];
        float brj = b_r[j * 8 + h],       bpj = b_p[j * 8 + h];
        A[j]  = 0.25f * ((laneQ == 0) ? arj : apj);
        Bp[j] = 0.25f * ((laneQ == 0) ? brj : -bpj);
      }
      #pragma unroll
      for (int tt = 0; tt < 4; ++tt) {
        short8 m;
        #pragma unroll
        for (int j = 0; j < 4; ++j) {
          m[j]     = bsh(A[j] * f8[tt][j]     + Bp[j] * f8[tt][4 + j]);
          m[4 + j] = bsh(A[j] * f8[tt][4 + j] - Bp[j] * f8[tt][j]);
        }
        kf1[tt] = (laneQ < 2) ? m : zero8;
      }
    }

    // ---- S = Q~ K~^T (wave-internal LDS readback) ----
    short8 qf0[4], kf0[4], vb[2][2];
    #pragma unroll
    for (int mt = 0; mt < 4; ++mt) {
      int t = mt * 16 + laneN;
      qf0[mt] = *(const short8*)&Qs[t * 32 + ((laneQ ^ (t & 3)) << 3)];
      kf0[mt] = *(const short8*)&Ks[t * 32 + ((laneQ ^ (t & 3)) << 3)];
    }
    #pragma unroll
    for (int ont = 0; ont < 2; ++ont)
      #pragma unroll
      for (int k2 = 0; k2 < 2; ++k2) {
        int d = ont * 16 + laneN;
        vb[ont][k2] = *(const short8*)&Vs[d * 64 + (((k2 * 4 + laneQ) ^ (d & 7)) << 3)];
      }

    floatx4 s[4][4];
    #pragma unroll
    for (int mt = 0; mt < 4; ++mt)
      #pragma unroll
      for (int nt = 0; nt < 4; ++nt) {
        s[mt][nt] = __builtin_amdgcn_mfma_f32_16x16x32_bf16(qf0[mt], kf0[nt], fzero, 0, 0, 0);
        s[mt][nt] = __builtin_amdgcn_mfma_f32_16x16x32_bf16(qf1[mt], kf1[nt], s[mt][nt], 0, 0, 0);
      }

    // ---- softmax -> P (swizzled overlay on Q||K) ----
    #pragma unroll
    for (int mt = 0; mt < 4; ++mt) {
      #pragma unroll
      for (int r = 0; r < 4; ++r) {
        float mx = fmaxf(fmaxf(s[mt][0][r], s[mt][1][r]), fmaxf(s[mt][2][r], s[mt][3][r]));
        mx = fmaxf(mx, __shfl_xor(mx, 1));
        mx = fmaxf(mx, __shfl_xor(mx, 2));
        mx = fmaxf(mx, __shfl_xor(mx, 4));
        mx = fmaxf(mx, __shfl_xor(mx, 8));
        float e0 = __expf(s[mt][0][r] - mx), e1 = __expf(s[mt][1][r] - mx);
        float e2 = __expf(s[mt][2][r] - mx), e3 = __expf(s[mt][3][r] - mx);
        float sum = e0 + e1 + e2 + e3;
        sum += __shfl_xor(sum, 1);
        sum += __shfl_xor(sum, 2);
        sum += __shfl_xor(sum, 4);
        sum += __shfl_xor(sum, 8);
        float inv = __builtin_amdgcn_rcpf(sum);
        int row = mt * 16 + laneQ * 4 + r;
        float ev[4] = {e0 * inv, e1 * inv, e2 * inv, e3 * inv};
        #pragma unroll
        for (int j = 0; j < 4; ++j) {
          int c8 = j * 2 + (laneN >> 3);
          Ps[row * 64 + ((c8 ^ (row & 7)) << 3) + (laneN & 7)] = __float2bfloat16(ev[j]);
        }
      }
    }

    // ---- O = P @ V ----
    #pragma unroll
    for (int mt = 0; mt < 4; ++mt) {
      int t = mt * 16 + laneN;
      short8 pf0 = *(const short8*)&Ps[t * 64 + ((laneQ ^ (t & 7)) << 3)];
      short8 pf1 = *(const short8*)&Ps[t * 64 + (((4 + laneQ) ^ (t & 7)) << 3)];
      #pragma unroll
      for (int ont = 0; ont < 2; ++ont) {
        oacc[hi][mt][ont] = __builtin_amdgcn_mfma_f32_16x16x32_bf16(pf0, vb[ont][0], fzero, 0, 0, 0);
        oacc[hi][mt][ont] = __builtin_amdgcn_mfma_f32_16x16x32_bf16(pf1, vb[ont][1], oacc[hi][mt][ont], 0, 0, 0);
      }
    }
  }

  // ---- O -> sO (overlays sX after all waves finish reading) ----
  __syncthreads();   // barrier 2
  #pragma unroll
  for (int hi = 0; hi < 2; ++hi)
    #pragma unroll
    for (int mt = 0; mt < 4; ++mt)
      #pragma unroll
      for (int ont = 0; ont < 2; ++ont)
        #pragma unroll
        for (int r = 0; r < 4; ++r) {
          int row = mt * 16 + laneQ * 4 + r;
          int c8 = (w * 2 + hi) * 4 + ont * 2 + (laneN >> 3);
          sX[row * 256 + ((c8 ^ (row & 7)) << 3) + (laneN & 7)] =
              __float2bfloat16(oacc[hi][mt][ont][r]);
        }
  __syncthreads();   // barrier 3

  // ---- proj: wave w -> out cols [w*64, w*64+64) ----
  floatx4 pacc[4][4];
  #pragma unroll
  for (int mt = 0; mt < 4; ++mt)
    #pragma unroll
    for (int nt = 0; nt < 4; ++nt) pacc[mt][nt] = fzero;
  #pragma unroll
  for (int kk = 0; kk < 8; ++kk) {
    short8 pa[4], pbf[4];
    #pragma unroll
    for (int mt = 0; mt < 4; ++mt) {
      int t = mt * 16 + laneN;
      pa[mt] = *(const short8*)&sX[t * 256 + (((kk * 4 + laneQ) ^ (t & 7)) << 3)];
    }
    #pragma unroll
    for (int nt = 0; nt < 4; ++nt)
      pbf[nt] = *(const short8*)&pwP[((size_t)((w * 4 + nt) * 8 + kk) * 64 + lane) * 8];
    #pragma unroll
    for (int mt = 0; mt < 4; ++mt)
      #pragma unroll
      for (int nt = 0; nt < 4; ++nt)
        pacc[mt][nt] = __builtin_amdgcn_mfma_f32_16x16x32_bf16(pa[mt], pbf[nt], pacc[mt][nt], 0, 0, 0);
  }
  float* og = out + (size_t)b * 16384;
  #pragma unroll
  for (int nt = 0; nt < 4; ++nt) {
    float bias = pb[w * 64 + nt * 16 + laneN];
    #pragma unroll
    for (int mt = 0; mt < 4; ++mt)
      #pragma unroll
      for (int r = 0; r < 4; ++r)
        og[(mt * 16 + laneQ * 4 + r) * 256 + w * 64 + nt * 16 + laneN] =
            pacc[mt][nt][r] + bias;
  }
}

extern "C" void kernel_launch(void* const* d_in, const int* in_sizes, int n_in,
                              void* d_out, int out_size, void* d_ws, size_t ws_size,
                              hipStream_t stream) {
  const float* x      = (const float*)d_in[0];
  const float* D      = (const float*)d_in[1];
  const float* a_p    = (const float*)d_in[2];
  const float* b_p    = (const float*)d_in[3];
  const float* a_r    = (const float*)d_in[4];
  const float* b_r    = (const float*)d_in[5];
  const float* qkv_w  = (const float*)d_in[6];
  const float* qkv_b  = (const float*)d_in[7];
  const float* proj_w = (const float*)d_in[8];
  const float* proj_b = (const float*)d_in[9];

  __hip_bfloat16* wqP = (__hip_bfloat16*)d_ws;   // 24576 chunks (qkv), then 8192 (proj)
  __hip_bfloat16* pwP = wqP + 196608;
  float* out = (float*)d_out;

  prep_kernel<<<128, 256, 0, stream>>>(qkv_w, proj_w, wqP);
  fused_kernel<<<1024, 256, 0, stream>>>(x, D, a_p, b_p, a_r, b_r, wqP, qkv_b,
                                         pwP, proj_b, out);
}